// Round 1
// baseline (362.568 us; speedup 1.0000x reference)
//
#include <hip/hip_runtime.h>
#include <math.h>

#define NB 8
#define PP 2048
#define DD 64
#define EPSF 1e-3f
#define RCPE 1000.0f
#define TMAX 10
#define THRESHF 0.1f
#define NEG_INF (-1e30f)
#define QSCALE 32767.5f                 // cost in [0,2] -> u16
#define S_DEQ  (1.0f / 32767.5f)
#define KR 512                          // row candidate cap
#define KC 512                          // col candidate cap (4 segs x 128)
#define TSEL 0.15f                      // selection margin (PROVEN: 0.12 fails, r6)
// NOTE (r8): cooperative grid.sync costs ~115 us/sync on gfx950. Do not retry.
// NOTE (r12): folding combine into 16-block weights => latency collapse.
// NOTE (r15): col select with 2B/lane strided loads => 2x regression.
// NOTE (r17): emd atomicAdd x4096 to ONE cacheline (out[0..7]) = 55us of
//             serialized RMW. Partials + 8-block finalize instead.
// NOTE (r18): cost_kernel was latency-bound at 18% occupancy (acc[4][4]=64
//             AGPR + 120 VGPR in unified file => 2 waves/SIMD). Now 128x64
//             tiles, acc[2][4]; row/col SUMS removed (algebraic: rowS=a.Sb).

typedef __attribute__((ext_vector_type(8))) short bf16x8;
typedef __attribute__((ext_vector_type(4))) float f32x4;

__device__ __forceinline__ float waveAllMax(float v) {
#pragma unroll
    for (int m = 1; m < 64; m <<= 1) v = fmaxf(v, __shfl_xor(v, m, 64));
    return v;
}
__device__ __forceinline__ float waveAllMin(float v) {
#pragma unroll
    for (int m = 1; m < 64; m <<= 1) v = fminf(v, __shfl_xor(v, m, 64));
    return v;
}
__device__ __forceinline__ float waveAllSum(float v) {
#pragma unroll
    for (int m = 1; m < 64; m <<= 1) v += __shfl_xor(v, m, 64);
    return v;
}
__device__ __forceinline__ short f2bf(float x) {   // round-to-nearest-even bf16
    unsigned b = __float_as_uint(x);
    return (short)((b + 0x7FFFu + ((b >> 16) & 1u)) >> 16);
}
__device__ __forceinline__ float bf2f(short h) {
    return __uint_as_float(((unsigned)(unsigned short)h) << 16);
}

// ---- L2 normalize + bf16 hi/lo split (+ init of u/v/conv/out/Sa/Sb) --------
__global__ void norm_kernel(const float* __restrict__ a, const float* __restrict__ b,
                            short* __restrict__ ahi, short* __restrict__ alo,
                            short* __restrict__ bhi, short* __restrict__ blo,
                            float* __restrict__ u, float* __restrict__ v,
                            int* __restrict__ conv, float* __restrict__ out,
                            float* __restrict__ Sa) {
    int gt = blockIdx.x * 256 + threadIdx.x;
    if (gt < NB * PP) { u[gt] = 0.0f; v[gt] = 0.0f; }
    if (gt == 0) *conv = 0;
    if (gt < NB) out[gt] = 0.0f;
    if (gt < 2 * NB * DD) Sa[gt] = 0.0f;       // Sa and Sb contiguous
    int wave = gt >> 6;
    int lane = threadIdx.x & 63;
    const float* src; short* dhi; short* dlo; int row;
    if (wave < NB * PP) { src = a; dhi = ahi; dlo = alo; row = wave; }
    else                { src = b; dhi = bhi; dlo = blo; row = wave - NB * PP; }
    float x = src[(size_t)row * DD + lane];
    float ss = waveAllSum(x * x);
    float r = 1.0f / fmaxf(sqrtf(ss), 1e-12f);
    float xn = x * r;
    short h = f2bf(xn);
    dhi[(size_t)row * DD + lane] = h;
    dlo[(size_t)row * DD + lane] = f2bf(xn - bf2f(h));
}

// ---- per-batch dim-wise sums: Sa[b][d] = sum_i a_n[i][d] (same for Sb) -----
__global__ void sumvec_kernel(const short* __restrict__ ahi, const short* __restrict__ alo,
                              const short* __restrict__ bhi, const short* __restrict__ blo,
                              float* __restrict__ Sa, float* __restrict__ Sb) {
    // 64 blocks: b (3b) | isB (1b) | quarter (2b)
    int b = blockIdx.x >> 3;
    bool isB = (blockIdx.x >> 2) & 1;
    int qtr = blockIdx.x & 3;
    const short* hi = (isB ? bhi : ahi) + ((size_t)b * PP + qtr * 512) * DD;
    const short* lo = (isB ? blo : alo) + ((size_t)b * PP + qtr * 512) * DD;
    float* dst = (isB ? Sb : Sa) + b * DD;
    int t = threadIdx.x;
    int w = t >> 6, lane = t & 63;
    int rl = lane >> 3, dq = lane & 7;       // row-in-group, dim-octet
    float s[8] = {};
#pragma unroll
    for (int it = 0; it < 16; ++it) {
        size_t o = (size_t)(w * 128 + it * 8 + rl) * DD + dq * 8;
        bf16x8 h = *(const bf16x8*)(hi + o);
        bf16x8 l = *(const bf16x8*)(lo + o);
#pragma unroll
        for (int e = 0; e < 8; ++e) s[e] += bf2f(h[e]) + bf2f(l[e]);
    }
#pragma unroll
    for (int e = 0; e < 8; ++e) {
#pragma unroll
        for (int m = 8; m < 64; m <<= 1) s[e] += __shfl_xor(s[e], m, 64);
    }
    __shared__ float sh[4][64];
    if (rl == 0) {
#pragma unroll
        for (int e = 0; e < 8; ++e) sh[w][dq * 8 + e] = s[e];
    }
    __syncthreads();
    if (t < 64) atomicAdd(&dst[t], sh[0][t] + sh[1][t] + sh[2][t] + sh[3][t]);
}

// ---- cost GEMM: 128x64 tile, wave tile 32x64, acc[2][4] (32 acc regs) ------
__global__ __launch_bounds__(256) void cost_kernel(const short* __restrict__ ahi,
        const short* __restrict__ alo, const short* __restrict__ bhi,
        const short* __restrict__ blo, unsigned short* __restrict__ C16,
        unsigned* __restrict__ rminp, unsigned* __restrict__ cminp) {
    __shared__ unsigned cmin2[4][64];
    int b  = blockIdx.z;
    int i0 = blockIdx.y * 128;
    int j0 = blockIdx.x * 64;
    int t = threadIdx.x, w = t >> 6, lane = t & 63;
    int quad = lane >> 4, li = lane & 15;
    size_t Aoff = ((size_t)b * PP + i0 + w * 32) * DD;
    size_t Boff = ((size_t)b * PP + j0) * DD;
    f32x4 acc[2][4] = {};
#pragma unroll
    for (int kc = 0; kc < 2; ++kc) {
        int k0 = kc * 32 + quad * 8;
        bf16x8 fah[2], fal[2];
#pragma unroll
        for (int mt = 0; mt < 2; ++mt) {
            size_t o = Aoff + (size_t)(mt * 16 + li) * DD + k0;
            fah[mt] = *(const bf16x8*)(ahi + o);
            fal[mt] = *(const bf16x8*)(alo + o);
        }
#pragma unroll
        for (int nt = 0; nt < 4; ++nt) {
            size_t o = Boff + (size_t)(li * 4 + nt) * DD + k0;
            bf16x8 fbh = *(const bf16x8*)(bhi + o);
            bf16x8 fbl = *(const bf16x8*)(blo + o);
#pragma unroll
            for (int mt = 0; mt < 2; ++mt) {
                acc[mt][nt] = __builtin_amdgcn_mfma_f32_16x16x32_bf16(
                        fah[mt], fbh, acc[mt][nt], 0, 0, 0);
                acc[mt][nt] = __builtin_amdgcn_mfma_f32_16x16x32_bf16(
                        fah[mt], fbl, acc[mt][nt], 0, 0, 0);
                acc[mt][nt] = __builtin_amdgcn_mfma_f32_16x16x32_bf16(
                        fal[mt], fbh, acc[mt][nt], 0, 0, 0);
            }
        }
    }
    // ---- epilogue: quant store + row/col min partials (sums removed) -------
    unsigned cmin[4] = {0xFFFFFFFFu, 0xFFFFFFFFu, 0xFFFFFFFFu, 0xFFFFFFFFu};
#pragma unroll
    for (int mt = 0; mt < 2; ++mt) {
#pragma unroll
        for (int r = 0; r < 4; ++r) {
            int irow = w * 32 + mt * 16 + quad * 4 + r;   // local row 0..127
            unsigned rm = 0xFFFFFFFFu;
            unsigned short qv[4];
#pragma unroll
            for (int nt = 0; nt < 4; ++nt) {
                float dot = acc[mt][nt][r];
                float cost = fminf(fmaxf(1.0f - dot, 0.0f), 2.0f);
                unsigned q = __float2uint_rn(cost * QSCALE);
                qv[nt] = (unsigned short)q;
                rm = min(rm, (q << 16) | (unsigned)(j0 + li * 4 + nt));
                cmin[nt] = min(cmin[nt], (q << 16) | (unsigned)(i0 + irow));
            }
            *(ushort4*)&C16[((size_t)b * PP + i0 + irow) * PP + j0 + li * 4] =
                make_ushort4(qv[0], qv[1], qv[2], qv[3]);
#pragma unroll
            for (int m = 1; m < 16; m <<= 1)
                rm = min(rm, (unsigned)__shfl_xor((int)rm, m, 64));
            if (li == 0)        // wave owns its rows exclusively: direct store
                rminp[(size_t)blockIdx.x * (NB * PP) + b * PP + i0 + irow] = rm;
        }
    }
#pragma unroll
    for (int nt = 0; nt < 4; ++nt) {
        unsigned cmv = cmin[nt];
        cmv = min(cmv, (unsigned)__shfl_xor((int)cmv, 16, 64));
        cmv = min(cmv, (unsigned)__shfl_xor((int)cmv, 32, 64));
        if (quad == 0) cmin2[w][li * 4 + nt] = cmv;
    }
    __syncthreads();
    if (t < 64)
        cminp[(size_t)blockIdx.y * (NB * PP) + b * PP + j0 + t] =
            min(min(cmin2[0][t], cmin2[1][t]), min(cmin2[2][t], cmin2[3][t]));
}

// ---- combine min partials (wide grid: 64 blocks) ---------------------------
__global__ void combine_kernel(const unsigned* __restrict__ rminp,
                               const unsigned* __restrict__ cminp,
                               unsigned* __restrict__ rowminp, unsigned* __restrict__ colminp) {
    int idx = blockIdx.x * 256 + threadIdx.x;
    unsigned rm = 0xFFFFFFFFu, cm = 0xFFFFFFFFu;
#pragma unroll
    for (int k = 0; k < 32; ++k)
        rm = min(rm, rminp[(size_t)k * (NB * PP) + idx]);
#pragma unroll
    for (int k = 0; k < 16; ++k)
        cm = min(cm, cminp[(size_t)k * (NB * PP) + idx]);
    rowminp[idx] = rm; colminp[idx] = cm;
}

// ---- weights + thresholds (rowS/colS computed algebraically: a_i . Sb) -----
__device__ __forceinline__ float blockReduceSum256(float v, float* sh) {
    v = waveAllSum(v);
    int lane = threadIdx.x & 63, w = threadIdx.x >> 6;
    if (lane == 0) sh[w] = v;
    __syncthreads();
    float r = sh[0] + sh[1] + sh[2] + sh[3];
    __syncthreads();
    return r;
}

__global__ void weights_kernel(const float* __restrict__ Sa, const float* __restrict__ Sb,
                               const short* __restrict__ ahi, const short* __restrict__ alo,
                               const short* __restrict__ bhi, const short* __restrict__ blo,
                               const unsigned* __restrict__ rowminp, const unsigned* __restrict__ colminp,
                               float* __restrict__ elm, float* __restrict__ eln,
                               float* __restrict__ rowminf, float* __restrict__ colminf,
                               float* __restrict__ cthresh) {
    __shared__ float sh[4];
    __shared__ float sv[64];
    int b = blockIdx.x & 7;
    bool isB = blockIdx.x >= 8;
    const short* hi = (isB ? bhi : ahi) + (size_t)b * PP * DD;
    const short* lo = (isB ? blo : alo) + (size_t)b * PP * DD;
    const float* svecg = (isB ? Sa : Sb) + b * DD;   // b_j . Sa  /  a_i . Sb
    float* dst = (isB ? eln : elm) + b * PP;
    int tid = threadIdx.x;
    if (tid < 64) sv[tid] = svecg[tid];
    __syncthreads();
    float x[8];
    float sabs = 0.0f;
#pragma unroll
    for (int q = 0; q < 8; ++q) {
        int row = tid + q * 256;
        float dot = 0.0f;
#pragma unroll
        for (int dq = 0; dq < 8; ++dq) {
            bf16x8 h = *(const bf16x8*)(hi + (size_t)row * DD + dq * 8);
            bf16x8 l = *(const bf16x8*)(lo + (size_t)row * DD + dq * 8);
#pragma unroll
            for (int e = 0; e < 8; ++e)
                dot += (bf2f(h[e]) + bf2f(l[e])) * sv[dq * 8 + e];
        }
        x[q] = dot * (1.0f / (float)PP);
        sabs += fabsf(x[q]);
    }
    sabs = blockReduceSum256(sabs, sh);
    float inv1 = 1.0f / fmaxf(sabs, 1e-12f);
    float spos = 0.0f;
#pragma unroll
    for (int q = 0; q < 8; ++q) {
        x[q] = fmaxf(x[q] * inv1, 0.0f);
        spos += x[q];
    }
    spos = blockReduceSum256(spos, sh);
    float inv2 = 1.0f / fmaxf(spos, 1e-12f);
#pragma unroll
    for (int q = 0; q < 8; ++q)
        dst[tid + q * 256] = EPSF * logf(x[q] * inv2 + 1e-8f);
    if (isB) {
#pragma unroll
        for (int q = 0; q < 8; ++q) {
            int idx = b * PP + tid + q * 256;
            unsigned pc = colminp[idx];
            unsigned arg = pc & 0xffffu;
            unsigned pr = rowminp[b * PP + arg];
            float cmf = (float)(pc >> 16) * S_DEQ;
            colminf[idx] = cmf;
            cthresh[idx] = cmf - (float)(pr >> 16) * S_DEQ + TSEL;
        }
    } else {
#pragma unroll
        for (int q = 0; q < 8; ++q) {
            int idx = b * PP + tid + q * 256;
            rowminf[idx] = (float)(rowminp[idx] >> 16) * S_DEQ;
        }
    }
}

// ---- fused candidate selection: blocks [0,4096) rows, [4096,5120) col qtrs -
__global__ __launch_bounds__(256) void select_kernel(const unsigned short* __restrict__ C16,
        const float* __restrict__ colminf, const float* __restrict__ rowminf,
        const float* __restrict__ cthresh,
        unsigned* __restrict__ rlist, int* __restrict__ rcnt,
        unsigned* __restrict__ clist, int* __restrict__ scnt) {
    __shared__ unsigned tile32[64][36];
    __shared__ float rm_s[64];
    __shared__ unsigned lcnt[64];
    if (blockIdx.x < 4096) {
        // ---- row path: wave per row, ballot compaction (r14-proven) --------
        int w = threadIdx.x >> 6, lane = threadIdx.x & 63;
        int row = blockIdx.x * 4 + w;
        int b = row >> 11;
        const uint4* cp = (const uint4*)(C16 + (size_t)row * PP);
        uint4 q4[4];
#pragma unroll
        for (int g = 0; g < 4; ++g) q4[g] = cp[g * 64 + lane];
        const float* cmb = colminf + b * PP;
        float rpmin = 1e30f;
#pragma unroll
        for (int g = 0; g < 4; ++g) {
            int jb = g * 512 + lane * 8;
            float4 cm0 = *(const float4*)(cmb + jb);
            float4 cm1 = *(const float4*)(cmb + jb + 4);
            float cm[8] = {cm0.x, cm0.y, cm0.z, cm0.w, cm1.x, cm1.y, cm1.z, cm1.w};
            unsigned qq[4] = {q4[g].x, q4[g].y, q4[g].z, q4[g].w};
#pragma unroll
            for (int h = 0; h < 4; ++h) {
                float c0 = (float)(qq[h] & 0xffffu) * S_DEQ;
                float c1 = (float)(qq[h] >> 16) * S_DEQ;
                rpmin = fminf(rpmin, fminf(c0 - cm[h * 2], c1 - cm[h * 2 + 1]));
            }
        }
        float rth = waveAllMin(rpmin) + TSEL;
        int base = 0;
#pragma unroll
        for (int g = 0; g < 4; ++g) {
            int jb = g * 512 + lane * 8;
            float4 cm0 = *(const float4*)(cmb + jb);
            float4 cm1 = *(const float4*)(cmb + jb + 4);
            float cm[8] = {cm0.x, cm0.y, cm0.z, cm0.w, cm1.x, cm1.y, cm1.z, cm1.w};
            unsigned qq[4] = {q4[g].x, q4[g].y, q4[g].z, q4[g].w};
#pragma unroll
            for (int e = 0; e < 8; ++e) {
                unsigned q = (qq[e >> 1] >> ((e & 1) * 16)) & 0xffffu;
                float cf = (float)q * S_DEQ;
                bool rq = (cf - cm[e]) <= rth;
                unsigned long long mb = __ballot(rq);
                if (rq) {
                    int pos = base + __popcll(mb & ((1ull << lane) - 1ull));
                    if (pos < KR) rlist[(size_t)row * KR + pos] = ((unsigned)(jb + e) << 16) | q;
                }
                base += __popcll(mb);
            }
        }
        if (lane == 0) rcnt[row] = base;
    } else {
        // ---- col path: (b, slab, quarter) block; 8 chunks, LDS transpose ---
        int bid = blockIdx.x - 4096;         // 0..1023
        int b = bid >> 7;
        int rem = bid & 127;
        int j0 = (rem >> 2) * 64;
        int r0 = (rem & 3) * 512;
        int qq = rem & 3;
        int t = threadIdx.x;
        int col = t & 63, seg = t >> 6;
        float ctj = cthresh[b * PP + j0 + col];
        unsigned* mylist = clist + ((size_t)(b * PP + j0 + col)) * KC + qq * 128;
        if (t < 64) lcnt[t] = 0;
        int lrow = t >> 3, lcc = t & 7;
        uint4 pf0, pf1; float pfr = 0.0f;
        {
            const unsigned short* base0 = C16 + ((size_t)b * PP + r0 + lrow) * PP + j0;
            pf0 = ((const uint4*)base0)[lcc];
            pf1 = ((const uint4*)(base0 + (size_t)32 * PP))[lcc];
            if (t < 64) pfr = rowminf[b * PP + r0 + t];
        }
        for (int chunk = 0; chunk < 8; ++chunk) {
            *(uint4*)&tile32[lrow][lcc * 4]      = pf0;
            *(uint4*)&tile32[32 + lrow][lcc * 4] = pf1;
            if (t < 64) rm_s[t] = pfr;
            __syncthreads();
            if (chunk < 7) {
                int rn = r0 + (chunk + 1) * 64;
                const unsigned short* base0 = C16 + ((size_t)b * PP + rn + lrow) * PP + j0;
                pf0 = ((const uint4*)base0)[lcc];
                pf1 = ((const uint4*)(base0 + (size_t)32 * PP))[lcc];
                if (t < 64) pfr = rowminf[b * PP + rn + t];
            }
            int rbase = r0 + chunk * 64;
#pragma unroll
            for (int rr = 0; rr < 16; ++rr) {
                int row = seg * 16 + rr;
                unsigned w32 = tile32[row][col >> 1];
                unsigned q = (col & 1) ? (w32 >> 16) : (w32 & 0xffffu);
                float cf = (float)q * S_DEQ;
                if (cf - rm_s[row] <= ctj) {
                    unsigned pos = atomicAdd(&lcnt[col], 1u);
                    if (pos < 128) mylist[pos] = ((unsigned)(rbase + row) << 16) | q;
                }
            }
            __syncthreads();
        }
        if (t < 64)
            scnt[(b * PP + j0 + t) * 4 + qq] = min((int)lcnt[t], 128);
    }
}

// ---- Sinkhorn u-update over row candidates (wave per row) ------------------
__global__ __launch_bounds__(256) void u_kernel(const unsigned* __restrict__ rlist,
        const int* __restrict__ rcnt, const float* __restrict__ v,
        const float* __restrict__ elm, float* __restrict__ u, float* __restrict__ du,
        const int* __restrict__ conv) {
    if (*conv) return;
    int w = threadIdx.x >> 6, lane = threadIdx.x & 63;
    int row = blockIdx.x * 4 + w;
    int b = row >> 11;
    int cnt = min(rcnt[row], KR);
    const unsigned* lst = rlist + (size_t)row * KR;
    const float* vb = v + (b << 11);
    float x[8];
    float m = NEG_INF;
#pragma unroll
    for (int s = 0; s < 8; ++s) {
        int e = lane + s * 64;
        x[s] = NEG_INF;
        if (e < cnt) {
            unsigned wd = lst[e];
            x[s] = vb[wd >> 16] - (float)(wd & 0xffffu) * S_DEQ;
        }
        m = fmaxf(m, x[s]);
    }
    m = waveAllMax(m);
    float s = 0.0f;
#pragma unroll
    for (int k = 0; k < 8; ++k) s += __expf((x[k] - m) * RCPE);
    s = waveAllSum(s);
    if (lane == 0) {
        float un = elm[row] - m - EPSF * logf(s);
        du[row] = fabsf(un - u[row]);
        u[row] = un;
    }
}

// ---- Sinkhorn v-update over col candidates (+ err/conv in block 0) ---------
__global__ __launch_bounds__(256) void v_kernel(const unsigned* __restrict__ clist,
        const int* __restrict__ scnt, const float* __restrict__ u,
        const float* __restrict__ eln, float* __restrict__ v,
        const float* __restrict__ du, int* __restrict__ conv) {
    if (*conv) return;
    int w = threadIdx.x >> 6, lane = threadIdx.x & 63;
    int jg = blockIdx.x * 4 + w;
    int b = jg >> 11;
    int4 sc = *(const int4*)&scnt[jg * 4];
    int cn[4] = {sc.x, sc.y, sc.z, sc.w};
    const unsigned* lst = clist + (size_t)jg * KC;
    const float* ub = u + (b << 11);
    float x[8];
    float m = NEG_INF;
#pragma unroll
    for (int s = 0; s < 8; ++s) {
        int e = lane + s * 64;
        int sg = e >> 7, k = e & 127;
        x[s] = NEG_INF;
        if (k < cn[sg]) {
            unsigned wd = lst[sg * 128 + k];
            x[s] = ub[wd >> 16] - (float)(wd & 0xffffu) * S_DEQ;
        }
        m = fmaxf(m, x[s]);
    }
    m = waveAllMax(m);
    float s = 0.0f;
#pragma unroll
    for (int k = 0; k < 8; ++k) s += __expf((x[k] - m) * RCPE);
    s = waveAllSum(s);
    if (lane == 0)
        v[jg] = eln[jg] - m - EPSF * logf(s);
    if (blockIdx.x == 0) {
        __shared__ float sh[4];
        int t = threadIdx.x;
        float sacc = 0.0f;
#pragma unroll
        for (int q = 0; q < 64; ++q) sacc += du[t + q * 256];
        sacc = waveAllSum(sacc);
        if (lane == 0) sh[w] = sacc;
        __syncthreads();
        if (t == 0) {
            float tot = sh[0] + sh[1] + sh[2] + sh[3];
            if (tot * (1.0f / (float)NB) < THRESHF) *conv = 1;
        }
    }
}

// ---- final: block partials (no atomics) + 8-block finalize -----------------
__global__ __launch_bounds__(256) void emd_kernel(const unsigned* __restrict__ rlist,
        const int* __restrict__ rcnt, const float* __restrict__ u,
        const float* __restrict__ v, float* __restrict__ epart) {
    __shared__ float sh[4];
    int w = threadIdx.x >> 6, lane = threadIdx.x & 63;
    int row = blockIdx.x * 4 + w;
    int b = row >> 11;
    int cnt = min(rcnt[row], KR);
    const unsigned* lst = rlist + (size_t)row * KR;
    const float* vb = v + (b << 11);
    float ui = u[row];
    float s = 0.0f;
#pragma unroll
    for (int k = 0; k < 8; ++k) {
        int e = lane + k * 64;
        if (e < cnt) {
            unsigned wd = lst[e];
            float cf = (float)(wd & 0xffffu) * S_DEQ;
            s += __expf((ui + vb[wd >> 16] - cf) * RCPE) * cf;
        }
    }
    s = waveAllSum(s);
    if (lane == 0) sh[w] = s;
    __syncthreads();
    if (threadIdx.x == 0) epart[blockIdx.x] = sh[0] + sh[1] + sh[2] + sh[3];
}

__global__ __launch_bounds__(256) void emd_finalize(const float* __restrict__ epart,
                                                    float* __restrict__ out) {
    __shared__ float sh[4];
    int b = blockIdx.x;
    int t = threadIdx.x;
    float s = epart[b * 512 + t] + epart[b * 512 + 256 + t];
    s = blockReduceSum256(s, sh);
    if (t == 0) out[b] = s;
}

extern "C" void kernel_launch(void* const* d_in, const int* in_sizes, int n_in,
                              void* d_out, int out_size, void* d_ws, size_t ws_size,
                              hipStream_t stream) {
    const float* a = (const float*)d_in[0];
    const float* b = (const float*)d_in[1];
    float* out = (float*)d_out;

    const size_t MBs = 1024ull * 1024ull;
    char* ws = (char*)d_ws;
    unsigned short* C16 = (unsigned short*)ws;              // 64 MB
    short* ahi   = (short*)(ws + 64 * MBs);                 // 2 MB each
    short* alo   = (short*)(ws + 66 * MBs);
    short* bhi   = (short*)(ws + 68 * MBs);
    short* blo   = (short*)(ws + 70 * MBs);
    unsigned* rminp = (unsigned*)(ws + 72 * MBs);           // 2 MB (32 jtiles)
    unsigned* cminp = (unsigned*)(ws + 74 * MBs);           // 1 MB (16 itiles)
    unsigned* rlist = (unsigned*)(ws + 64 * MBs);           // 32 MB, alias (after weights)
    unsigned* clist = (unsigned*)(ws + 96 * MBs);           // 32 MB
    char* tail = ws + 128 * MBs;
    size_t off = 0;
    const size_t szV = (size_t)NB * PP * 4;                 // 64 KB
    int*   scnt    = (int*)(tail + off); off += (size_t)NB * PP * 4 * 4;
    unsigned* rowminp = (unsigned*)(tail + off); off += szV;
    unsigned* colminp = (unsigned*)(tail + off); off += szV;
    float* rowminf = (float*)(tail + off); off += szV;
    float* colminf = (float*)(tail + off); off += szV;
    float* cthresh = (float*)(tail + off); off += szV;
    float* elm     = (float*)(tail + off); off += szV;
    float* eln     = (float*)(tail + off); off += szV;
    float* u       = (float*)(tail + off); off += szV;
    float* v       = (float*)(tail + off); off += szV;
    float* du      = (float*)(tail + off); off += szV;
    int*   rcnt    = (int*)(tail + off); off += szV;
    float* Sa      = (float*)(tail + off); off += (size_t)2 * NB * DD * 4; // Sa+Sb
    float* Sb      = Sa + NB * DD;
    float* epart   = (float*)(tail + off); off += (size_t)NB * PP / 4 * 4;
    int*   conv    = (int*)(tail + off); off += 64;
    if (ws_size < 128 * MBs + off) return;

    norm_kernel<<<(2 * NB * PP) / 4, 256, 0, stream>>>(a, b, ahi, alo, bhi, blo,
            u, v, conv, out, Sa);
    sumvec_kernel<<<64, 256, 0, stream>>>(ahi, alo, bhi, blo, Sa, Sb);
    cost_kernel<<<dim3(PP / 64, PP / 128, NB), 256, 0, stream>>>(
            ahi, alo, bhi, blo, C16, rminp, cminp);
    combine_kernel<<<64, 256, 0, stream>>>(rminp, cminp, rowminp, colminp);
    weights_kernel<<<16, 256, 0, stream>>>(Sa, Sb, ahi, alo, bhi, blo,
            rowminp, colminp, elm, eln, rowminf, colminf, cthresh);
    select_kernel<<<4096 + 1024, 256, 0, stream>>>(C16, colminf, rowminf,
            cthresh, rlist, rcnt, clist, scnt);
    for (int it = 0; it < TMAX; ++it) {
        u_kernel<<<NB * PP / 4, 256, 0, stream>>>(rlist, rcnt, v, elm, u, du, conv);
        v_kernel<<<NB * PP / 4, 256, 0, stream>>>(clist, scnt, u, eln, v, du, conv);
    }
    emd_kernel<<<NB * PP / 4, 256, 0, stream>>>(rlist, rcnt, u, v, epart);
    emd_finalize<<<NB, 256, 0, stream>>>(epart, out);
}

// Round 2
// 335.631 us; speedup vs baseline: 1.0803x; 1.0803x over previous
//
#include <hip/hip_runtime.h>
#include <math.h>

#define NB 8
#define PP 2048
#define DD 64
#define EPSF 1e-3f
#define RCPE 1000.0f
#define TMAX 10
#define THRESHF 0.1f
#define NEG_INF (-1e30f)
#define QSCALE 32767.5f                 // cost in [0,2] -> u16
#define S_DEQ  (1.0f / 32767.5f)
#define KR 512                          // row candidate cap
#define KC 512                          // col candidate cap (4 segs x 128)
#define TSEL 0.15f                      // selection margin (PROVEN: 0.12 fails, r6)
// NOTE (r8): cooperative grid.sync costs ~115 us/sync on gfx950. Do not retry.
// NOTE (r12): folding combine into 16-block weights => latency collapse.
// NOTE (r15): col select with 2B/lane strided loads => 2x regression.
// NOTE (r17): emd atomicAdd x4096 to ONE cacheline (out[0..7]) = 55us of
//             serialized RMW. Partials + 8-block finalize instead.
// NOTE (r18): cost_kernel occupancy 18->37% (VGPR 120->52) left dur FLAT at
//             56us. NOT occupancy-bound. Suspects: per-wave load serialization
//             (ILP) or HBM write-path ceiling (WRITE_SIZE pinned 68MB).
// NOTE (r19): this round: LDS-staged B panel (XOR swizzle (row&7)<<4, reg-
//             staged writes), 128x128 tile, pknorm epilogue. If dur still
//             ~55us with WRITE pinned => write wall; eliminate C16 next.

typedef __attribute__((ext_vector_type(8))) short bf16x8;
typedef __attribute__((ext_vector_type(4))) float f32x4;

__device__ __forceinline__ float waveAllMax(float v) {
#pragma unroll
    for (int m = 1; m < 64; m <<= 1) v = fmaxf(v, __shfl_xor(v, m, 64));
    return v;
}
__device__ __forceinline__ float waveAllMin(float v) {
#pragma unroll
    for (int m = 1; m < 64; m <<= 1) v = fminf(v, __shfl_xor(v, m, 64));
    return v;
}
__device__ __forceinline__ float waveAllSum(float v) {
#pragma unroll
    for (int m = 1; m < 64; m <<= 1) v += __shfl_xor(v, m, 64);
    return v;
}
__device__ __forceinline__ short f2bf(float x) {   // round-to-nearest-even bf16
    unsigned b = __float_as_uint(x);
    return (short)((b + 0x7FFFu + ((b >> 16) & 1u)) >> 16);
}
__device__ __forceinline__ float bf2f(short h) {
    return __uint_as_float(((unsigned)(unsigned short)h) << 16);
}
// fused: clamp(f,0,1)*65535, round, pack 2 -> u32  (== round(cost*32767.5))
__device__ __forceinline__ unsigned pknorm_u16(float a, float b) {
    unsigned r;
    asm("v_cvt_pknorm_u16_f32 %0, %1, %2" : "=v"(r) : "v"(a), "v"(b));
    return r;
}

// ---- L2 normalize + bf16 hi/lo split (+ init of u/v/conv/out/Sa/Sb) --------
__global__ void norm_kernel(const float* __restrict__ a, const float* __restrict__ b,
                            short* __restrict__ ahi, short* __restrict__ alo,
                            short* __restrict__ bhi, short* __restrict__ blo,
                            float* __restrict__ u, float* __restrict__ v,
                            int* __restrict__ conv, float* __restrict__ out,
                            float* __restrict__ Sa) {
    int gt = blockIdx.x * 256 + threadIdx.x;
    if (gt < NB * PP) { u[gt] = 0.0f; v[gt] = 0.0f; }
    if (gt == 0) *conv = 0;
    if (gt < NB) out[gt] = 0.0f;
    if (gt < 2 * NB * DD) Sa[gt] = 0.0f;       // Sa and Sb contiguous
    int wave = gt >> 6;
    int lane = threadIdx.x & 63;
    const float* src; short* dhi; short* dlo; int row;
    if (wave < NB * PP) { src = a; dhi = ahi; dlo = alo; row = wave; }
    else                { src = b; dhi = bhi; dlo = blo; row = wave - NB * PP; }
    float x = src[(size_t)row * DD + lane];
    float ss = waveAllSum(x * x);
    float r = 1.0f / fmaxf(sqrtf(ss), 1e-12f);
    float xn = x * r;
    short h = f2bf(xn);
    dhi[(size_t)row * DD + lane] = h;
    dlo[(size_t)row * DD + lane] = f2bf(xn - bf2f(h));
}

// ---- per-batch dim-wise sums: Sa[b][d] = sum_i a_n[i][d] (same for Sb) -----
__global__ void sumvec_kernel(const short* __restrict__ ahi, const short* __restrict__ alo,
                              const short* __restrict__ bhi, const short* __restrict__ blo,
                              float* __restrict__ Sa, float* __restrict__ Sb) {
    // 64 blocks: b (3b) | isB (1b) | quarter (2b)
    int b = blockIdx.x >> 3;
    bool isB = (blockIdx.x >> 2) & 1;
    int qtr = blockIdx.x & 3;
    const short* hi = (isB ? bhi : ahi) + ((size_t)b * PP + qtr * 512) * DD;
    const short* lo = (isB ? blo : alo) + ((size_t)b * PP + qtr * 512) * DD;
    float* dst = (isB ? Sb : Sa) + b * DD;
    int t = threadIdx.x;
    int w = t >> 6, lane = t & 63;
    int rl = lane >> 3, dq = lane & 7;       // row-in-group, dim-octet
    float s[8] = {};
#pragma unroll
    for (int it = 0; it < 16; ++it) {
        size_t o = (size_t)(w * 128 + it * 8 + rl) * DD + dq * 8;
        bf16x8 h = *(const bf16x8*)(hi + o);
        bf16x8 l = *(const bf16x8*)(lo + o);
#pragma unroll
        for (int e = 0; e < 8; ++e) s[e] += bf2f(h[e]) + bf2f(l[e]);
    }
#pragma unroll
    for (int e = 0; e < 8; ++e) {
#pragma unroll
        for (int m = 8; m < 64; m <<= 1) s[e] += __shfl_xor(s[e], m, 64);
    }
    __shared__ float sh[4][64];
    if (rl == 0) {
#pragma unroll
        for (int e = 0; e < 8; ++e) sh[w][dq * 8 + e] = s[e];
    }
    __syncthreads();
    if (t < 64) atomicAdd(&dst[t], sh[0][t] + sh[1][t] + sh[2][t] + sh[3][t]);
}

// ---- cost GEMM: 128x128 tile, LDS-staged B (XOR swizzle), pknorm epilogue --
// wave w owns rows [w*32, w*32+32); cols split nh*64 + li*4 + ntl.
__global__ __launch_bounds__(256, 4) void cost_kernel(const short* __restrict__ ahi,
        const short* __restrict__ alo, const short* __restrict__ bhi,
        const short* __restrict__ blo, unsigned short* __restrict__ C16,
        unsigned* __restrict__ rminp, unsigned* __restrict__ cminp) {
    __shared__ short Bs[2][128 * 64];        // [hi/lo][col][dim], LDS[x]=G[swz(x)]
    __shared__ unsigned cmin2[4][128];
    int b  = blockIdx.z;
    int i0 = blockIdx.y * 128;
    int j0 = blockIdx.x * 128;
    int t = threadIdx.x, w = t >> 6, lane = t & 63;
    int quad = lane >> 4, li = lane & 15;
    // ---- stage B panel (hi+lo, 32 KB) with write-side inverse swizzle ------
    const char* bh = (const char*)(bhi + ((size_t)b * PP + j0) * DD);
    const char* bl = (const char*)(blo + ((size_t)b * PP + j0) * DD);
    uint4 st[8];
#pragma unroll
    for (int i = 0; i < 4; ++i) {
        unsigned x = (unsigned)(t + i * 256) * 16;
        unsigned sx = x ^ (((x >> 7) & 7u) << 4);
        st[i]     = *(const uint4*)(bh + sx);
        st[4 + i] = *(const uint4*)(bl + sx);
    }
#pragma unroll
    for (int i = 0; i < 4; ++i) {
        unsigned x = (unsigned)(t + i * 256) * 16;
        *(uint4*)((char*)&Bs[0][0] + x) = st[i];
        *(uint4*)((char*)&Bs[1][0] + x) = st[4 + i];
    }
    __syncthreads();
    // ---- MFMA main: bf16 hi/lo split (hh + hl + lh) ------------------------
    size_t Aoff = ((size_t)b * PP + i0 + w * 32) * DD;
    f32x4 acc[2][2][4] = {};                 // [mt][nh][ntl]
#pragma unroll
    for (int kc = 0; kc < 2; ++kc) {
        int k0 = kc * 32 + quad * 8;
        bf16x8 fah[2], fal[2];
#pragma unroll
        for (int mt = 0; mt < 2; ++mt) {
            size_t o = Aoff + (size_t)(mt * 16 + li) * DD + k0;
            fah[mt] = *(const bf16x8*)(ahi + o);
            fal[mt] = *(const bf16x8*)(alo + o);
        }
#pragma unroll
        for (int nh = 0; nh < 2; ++nh) {
#pragma unroll
            for (int ntl = 0; ntl < 4; ++ntl) {
                int col = nh * 64 + li * 4 + ntl;
                unsigned xo = ((unsigned)col * 128 + (unsigned)(kc * 4 + quad) * 16)
                              ^ (((unsigned)col & 7u) << 4);
                bf16x8 fbh = *(const bf16x8*)((const char*)&Bs[0][0] + xo);
                bf16x8 fbl = *(const bf16x8*)((const char*)&Bs[1][0] + xo);
#pragma unroll
                for (int mt = 0; mt < 2; ++mt) {
                    acc[mt][nh][ntl] = __builtin_amdgcn_mfma_f32_16x16x32_bf16(
                            fah[mt], fbh, acc[mt][nh][ntl], 0, 0, 0);
                    acc[mt][nh][ntl] = __builtin_amdgcn_mfma_f32_16x16x32_bf16(
                            fah[mt], fbl, acc[mt][nh][ntl], 0, 0, 0);
                    acc[mt][nh][ntl] = __builtin_amdgcn_mfma_f32_16x16x32_bf16(
                            fal[mt], fbh, acc[mt][nh][ntl], 0, 0, 0);
                }
            }
        }
    }
    // ---- epilogue: pknorm quant+pack store + row/col min partials ----------
    unsigned cmin[2][4] = {{0xFFFFFFFFu, 0xFFFFFFFFu, 0xFFFFFFFFu, 0xFFFFFFFFu},
                           {0xFFFFFFFFu, 0xFFFFFFFFu, 0xFFFFFFFFu, 0xFFFFFFFFu}};
#pragma unroll
    for (int mt = 0; mt < 2; ++mt) {
#pragma unroll
        for (int r = 0; r < 4; ++r) {
            int irow = w * 32 + mt * 16 + quad * 4 + r;   // local row 0..127
            unsigned rm = 0xFFFFFFFFu;
            unsigned rowkey = (unsigned)(i0 + irow);
#pragma unroll
            for (int nh = 0; nh < 2; ++nh) {
                float f0 = fmaf(acc[mt][nh][0][r], -0.5f, 0.5f);
                float f1 = fmaf(acc[mt][nh][1][r], -0.5f, 0.5f);
                float f2 = fmaf(acc[mt][nh][2][r], -0.5f, 0.5f);
                float f3 = fmaf(acc[mt][nh][3][r], -0.5f, 0.5f);
                unsigned w0 = pknorm_u16(f0, f1);
                unsigned w1 = pknorm_u16(f2, f3);
                uint2 pv; pv.x = w0; pv.y = w1;
                *(uint2*)&C16[((size_t)b * PP + i0 + irow) * PP + j0 + nh * 64 + li * 4] = pv;
                unsigned colb = (unsigned)(j0 + nh * 64 + li * 4);
                unsigned lo0 = w0 << 16, hi0 = w0 & 0xFFFF0000u;
                unsigned lo1 = w1 << 16, hi1 = w1 & 0xFFFF0000u;
                rm = min(rm, min(min(lo0 | colb, hi0 | (colb + 1)),
                                 min(lo1 | (colb + 2), hi1 | (colb + 3))));
                cmin[nh][0] = min(cmin[nh][0], lo0 | rowkey);
                cmin[nh][1] = min(cmin[nh][1], hi0 | rowkey);
                cmin[nh][2] = min(cmin[nh][2], lo1 | rowkey);
                cmin[nh][3] = min(cmin[nh][3], hi1 | rowkey);
            }
#pragma unroll
            for (int m = 1; m < 16; m <<= 1)
                rm = min(rm, (unsigned)__shfl_xor((int)rm, m, 64));
            if (li == 0)        // wave owns its rows exclusively: direct store
                rminp[(size_t)blockIdx.x * (NB * PP) + b * PP + i0 + irow] = rm;
        }
    }
#pragma unroll
    for (int nh = 0; nh < 2; ++nh) {
#pragma unroll
        for (int ntl = 0; ntl < 4; ++ntl) {
            unsigned cmv = cmin[nh][ntl];
            cmv = min(cmv, (unsigned)__shfl_xor((int)cmv, 16, 64));
            cmv = min(cmv, (unsigned)__shfl_xor((int)cmv, 32, 64));
            if (quad == 0) cmin2[w][nh * 64 + li * 4 + ntl] = cmv;
        }
    }
    __syncthreads();
    if (t < 128)
        cminp[(size_t)blockIdx.y * (NB * PP) + b * PP + j0 + t] =
            min(min(cmin2[0][t], cmin2[1][t]), min(cmin2[2][t], cmin2[3][t]));
}

// ---- combine min partials (wide grid: 64 blocks) ---------------------------
__global__ void combine_kernel(const unsigned* __restrict__ rminp,
                               const unsigned* __restrict__ cminp,
                               unsigned* __restrict__ rowminp, unsigned* __restrict__ colminp) {
    int idx = blockIdx.x * 256 + threadIdx.x;
    unsigned rm = 0xFFFFFFFFu, cm = 0xFFFFFFFFu;
#pragma unroll
    for (int k = 0; k < 16; ++k)
        rm = min(rm, rminp[(size_t)k * (NB * PP) + idx]);
#pragma unroll
    for (int k = 0; k < 16; ++k)
        cm = min(cm, cminp[(size_t)k * (NB * PP) + idx]);
    rowminp[idx] = rm; colminp[idx] = cm;
}

// ---- weights + thresholds (rowS/colS computed algebraically: a_i . Sb) -----
__device__ __forceinline__ float blockReduceSum256(float v, float* sh) {
    v = waveAllSum(v);
    int lane = threadIdx.x & 63, w = threadIdx.x >> 6;
    if (lane == 0) sh[w] = v;
    __syncthreads();
    float r = sh[0] + sh[1] + sh[2] + sh[3];
    __syncthreads();
    return r;
}

__global__ void weights_kernel(const float* __restrict__ Sa, const float* __restrict__ Sb,
                               const short* __restrict__ ahi, const short* __restrict__ alo,
                               const short* __restrict__ bhi, const short* __restrict__ blo,
                               const unsigned* __restrict__ rowminp, const unsigned* __restrict__ colminp,
                               float* __restrict__ elm, float* __restrict__ eln,
                               float* __restrict__ rowminf, float* __restrict__ colminf,
                               float* __restrict__ cthresh) {
    __shared__ float sh[4];
    __shared__ float sv[64];
    int b = blockIdx.x & 7;
    bool isB = blockIdx.x >= 8;
    const short* hi = (isB ? bhi : ahi) + (size_t)b * PP * DD;
    const short* lo = (isB ? blo : alo) + (size_t)b * PP * DD;
    const float* svecg = (isB ? Sa : Sb) + b * DD;   // b_j . Sa  /  a_i . Sb
    float* dst = (isB ? eln : elm) + b * PP;
    int tid = threadIdx.x;
    if (tid < 64) sv[tid] = svecg[tid];
    __syncthreads();
    float x[8];
    float sabs = 0.0f;
#pragma unroll
    for (int q = 0; q < 8; ++q) {
        int row = tid + q * 256;
        float dot = 0.0f;
#pragma unroll
        for (int dq = 0; dq < 8; ++dq) {
            bf16x8 h = *(const bf16x8*)(hi + (size_t)row * DD + dq * 8);
            bf16x8 l = *(const bf16x8*)(lo + (size_t)row * DD + dq * 8);
#pragma unroll
            for (int e = 0; e < 8; ++e)
                dot += (bf2f(h[e]) + bf2f(l[e])) * sv[dq * 8 + e];
        }
        x[q] = dot * (1.0f / (float)PP);
        sabs += fabsf(x[q]);
    }
    sabs = blockReduceSum256(sabs, sh);
    float inv1 = 1.0f / fmaxf(sabs, 1e-12f);
    float spos = 0.0f;
#pragma unroll
    for (int q = 0; q < 8; ++q) {
        x[q] = fmaxf(x[q] * inv1, 0.0f);
        spos += x[q];
    }
    spos = blockReduceSum256(spos, sh);
    float inv2 = 1.0f / fmaxf(spos, 1e-12f);
#pragma unroll
    for (int q = 0; q < 8; ++q)
        dst[tid + q * 256] = EPSF * logf(x[q] * inv2 + 1e-8f);
    if (isB) {
#pragma unroll
        for (int q = 0; q < 8; ++q) {
            int idx = b * PP + tid + q * 256;
            unsigned pc = colminp[idx];
            unsigned arg = pc & 0xffffu;
            unsigned pr = rowminp[b * PP + arg];
            float cmf = (float)(pc >> 16) * S_DEQ;
            colminf[idx] = cmf;
            cthresh[idx] = cmf - (float)(pr >> 16) * S_DEQ + TSEL;
        }
    } else {
#pragma unroll
        for (int q = 0; q < 8; ++q) {
            int idx = b * PP + tid + q * 256;
            rowminf[idx] = (float)(rowminp[idx] >> 16) * S_DEQ;
        }
    }
}

// ---- fused candidate selection: blocks [0,4096) rows, [4096,5120) col qtrs -
__global__ __launch_bounds__(256) void select_kernel(const unsigned short* __restrict__ C16,
        const float* __restrict__ colminf, const float* __restrict__ rowminf,
        const float* __restrict__ cthresh,
        unsigned* __restrict__ rlist, int* __restrict__ rcnt,
        unsigned* __restrict__ clist, int* __restrict__ scnt) {
    __shared__ unsigned tile32[64][36];
    __shared__ float rm_s[64];
    __shared__ unsigned lcnt[64];
    if (blockIdx.x < 4096) {
        // ---- row path: wave per row, ballot compaction (r14-proven) --------
        int w = threadIdx.x >> 6, lane = threadIdx.x & 63;
        int row = blockIdx.x * 4 + w;
        int b = row >> 11;
        const uint4* cp = (const uint4*)(C16 + (size_t)row * PP);
        uint4 q4[4];
#pragma unroll
        for (int g = 0; g < 4; ++g) q4[g] = cp[g * 64 + lane];
        const float* cmb = colminf + b * PP;
        float rpmin = 1e30f;
#pragma unroll
        for (int g = 0; g < 4; ++g) {
            int jb = g * 512 + lane * 8;
            float4 cm0 = *(const float4*)(cmb + jb);
            float4 cm1 = *(const float4*)(cmb + jb + 4);
            float cm[8] = {cm0.x, cm0.y, cm0.z, cm0.w, cm1.x, cm1.y, cm1.z, cm1.w};
            unsigned qq[4] = {q4[g].x, q4[g].y, q4[g].z, q4[g].w};
#pragma unroll
            for (int h = 0; h < 4; ++h) {
                float c0 = (float)(qq[h] & 0xffffu) * S_DEQ;
                float c1 = (float)(qq[h] >> 16) * S_DEQ;
                rpmin = fminf(rpmin, fminf(c0 - cm[h * 2], c1 - cm[h * 2 + 1]));
            }
        }
        float rth = waveAllMin(rpmin) + TSEL;
        int base = 0;
#pragma unroll
        for (int g = 0; g < 4; ++g) {
            int jb = g * 512 + lane * 8;
            float4 cm0 = *(const float4*)(cmb + jb);
            float4 cm1 = *(const float4*)(cmb + jb + 4);
            float cm[8] = {cm0.x, cm0.y, cm0.z, cm0.w, cm1.x, cm1.y, cm1.z, cm1.w};
            unsigned qq[4] = {q4[g].x, q4[g].y, q4[g].z, q4[g].w};
#pragma unroll
            for (int e = 0; e < 8; ++e) {
                unsigned q = (qq[e >> 1] >> ((e & 1) * 16)) & 0xffffu;
                float cf = (float)q * S_DEQ;
                bool rq = (cf - cm[e]) <= rth;
                unsigned long long mb = __ballot(rq);
                if (rq) {
                    int pos = base + __popcll(mb & ((1ull << lane) - 1ull));
                    if (pos < KR) rlist[(size_t)row * KR + pos] = ((unsigned)(jb + e) << 16) | q;
                }
                base += __popcll(mb);
            }
        }
        if (lane == 0) rcnt[row] = base;
    } else {
        // ---- col path: (b, slab, quarter) block; 8 chunks, LDS transpose ---
        int bid = blockIdx.x - 4096;         // 0..1023
        int b = bid >> 7;
        int rem = bid & 127;
        int j0 = (rem >> 2) * 64;
        int r0 = (rem & 3) * 512;
        int qq = rem & 3;
        int t = threadIdx.x;
        int col = t & 63, seg = t >> 6;
        float ctj = cthresh[b * PP + j0 + col];
        unsigned* mylist = clist + ((size_t)(b * PP + j0 + col)) * KC + qq * 128;
        if (t < 64) lcnt[t] = 0;
        int lrow = t >> 3, lcc = t & 7;
        uint4 pf0, pf1; float pfr = 0.0f;
        {
            const unsigned short* base0 = C16 + ((size_t)b * PP + r0 + lrow) * PP + j0;
            pf0 = ((const uint4*)base0)[lcc];
            pf1 = ((const uint4*)(base0 + (size_t)32 * PP))[lcc];
            if (t < 64) pfr = rowminf[b * PP + r0 + t];
        }
        for (int chunk = 0; chunk < 8; ++chunk) {
            *(uint4*)&tile32[lrow][lcc * 4]      = pf0;
            *(uint4*)&tile32[32 + lrow][lcc * 4] = pf1;
            if (t < 64) rm_s[t] = pfr;
            __syncthreads();
            if (chunk < 7) {
                int rn = r0 + (chunk + 1) * 64;
                const unsigned short* base0 = C16 + ((size_t)b * PP + rn + lrow) * PP + j0;
                pf0 = ((const uint4*)base0)[lcc];
                pf1 = ((const uint4*)(base0 + (size_t)32 * PP))[lcc];
                if (t < 64) pfr = rowminf[b * PP + rn + t];
            }
            int rbase = r0 + chunk * 64;
#pragma unroll
            for (int rr = 0; rr < 16; ++rr) {
                int row = seg * 16 + rr;
                unsigned w32 = tile32[row][col >> 1];
                unsigned q = (col & 1) ? (w32 >> 16) : (w32 & 0xffffu);
                float cf = (float)q * S_DEQ;
                if (cf - rm_s[row] <= ctj) {
                    unsigned pos = atomicAdd(&lcnt[col], 1u);
                    if (pos < 128) mylist[pos] = ((unsigned)(rbase + row) << 16) | q;
                }
            }
            __syncthreads();
        }
        if (t < 64)
            scnt[(b * PP + j0 + t) * 4 + qq] = min((int)lcnt[t], 128);
    }
}

// ---- Sinkhorn u-update over row candidates (wave per row) ------------------
__global__ __launch_bounds__(256) void u_kernel(const unsigned* __restrict__ rlist,
        const int* __restrict__ rcnt, const float* __restrict__ v,
        const float* __restrict__ elm, float* __restrict__ u, float* __restrict__ du,
        const int* __restrict__ conv) {
    if (*conv) return;
    int w = threadIdx.x >> 6, lane = threadIdx.x & 63;
    int row = blockIdx.x * 4 + w;
    int b = row >> 11;
    int cnt = min(rcnt[row], KR);
    const unsigned* lst = rlist + (size_t)row * KR;
    const float* vb = v + (b << 11);
    float x[8];
    float m = NEG_INF;
#pragma unroll
    for (int s = 0; s < 8; ++s) {
        int e = lane + s * 64;
        x[s] = NEG_INF;
        if (e < cnt) {
            unsigned wd = lst[e];
            x[s] = vb[wd >> 16] - (float)(wd & 0xffffu) * S_DEQ;
        }
        m = fmaxf(m, x[s]);
    }
    m = waveAllMax(m);
    float s = 0.0f;
#pragma unroll
    for (int k = 0; k < 8; ++k) s += __expf((x[k] - m) * RCPE);
    s = waveAllSum(s);
    if (lane == 0) {
        float un = elm[row] - m - EPSF * logf(s);
        du[row] = fabsf(un - u[row]);
        u[row] = un;
    }
}

// ---- Sinkhorn v-update over col candidates (+ err/conv in block 0) ---------
__global__ __launch_bounds__(256) void v_kernel(const unsigned* __restrict__ clist,
        const int* __restrict__ scnt, const float* __restrict__ u,
        const float* __restrict__ eln, float* __restrict__ v,
        const float* __restrict__ du, int* __restrict__ conv) {
    if (*conv) return;
    int w = threadIdx.x >> 6, lane = threadIdx.x & 63;
    int jg = blockIdx.x * 4 + w;
    int b = jg >> 11;
    int4 sc = *(const int4*)&scnt[jg * 4];
    int cn[4] = {sc.x, sc.y, sc.z, sc.w};
    const unsigned* lst = clist + (size_t)jg * KC;
    const float* ub = u + (b << 11);
    float x[8];
    float m = NEG_INF;
#pragma unroll
    for (int s = 0; s < 8; ++s) {
        int e = lane + s * 64;
        int sg = e >> 7, k = e & 127;
        x[s] = NEG_INF;
        if (k < cn[sg]) {
            unsigned wd = lst[sg * 128 + k];
            x[s] = ub[wd >> 16] - (float)(wd & 0xffffu) * S_DEQ;
        }
        m = fmaxf(m, x[s]);
    }
    m = waveAllMax(m);
    float s = 0.0f;
#pragma unroll
    for (int k = 0; k < 8; ++k) s += __expf((x[k] - m) * RCPE);
    s = waveAllSum(s);
    if (lane == 0)
        v[jg] = eln[jg] - m - EPSF * logf(s);
    if (blockIdx.x == 0) {
        __shared__ float sh[4];
        int t = threadIdx.x;
        float sacc = 0.0f;
#pragma unroll
        for (int q = 0; q < 64; ++q) sacc += du[t + q * 256];
        sacc = waveAllSum(sacc);
        if (lane == 0) sh[w] = sacc;
        __syncthreads();
        if (t == 0) {
            float tot = sh[0] + sh[1] + sh[2] + sh[3];
            if (tot * (1.0f / (float)NB) < THRESHF) *conv = 1;
        }
    }
}

// ---- final: block partials (no atomics) + 8-block finalize -----------------
__global__ __launch_bounds__(256) void emd_kernel(const unsigned* __restrict__ rlist,
        const int* __restrict__ rcnt, const float* __restrict__ u,
        const float* __restrict__ v, float* __restrict__ epart) {
    __shared__ float sh[4];
    int w = threadIdx.x >> 6, lane = threadIdx.x & 63;
    int row = blockIdx.x * 4 + w;
    int b = row >> 11;
    int cnt = min(rcnt[row], KR);
    const unsigned* lst = rlist + (size_t)row * KR;
    const float* vb = v + (b << 11);
    float ui = u[row];
    float s = 0.0f;
#pragma unroll
    for (int k = 0; k < 8; ++k) {
        int e = lane + k * 64;
        if (e < cnt) {
            unsigned wd = lst[e];
            float cf = (float)(wd & 0xffffu) * S_DEQ;
            s += __expf((ui + vb[wd >> 16] - cf) * RCPE) * cf;
        }
    }
    s = waveAllSum(s);
    if (lane == 0) sh[w] = s;
    __syncthreads();
    if (threadIdx.x == 0) epart[blockIdx.x] = sh[0] + sh[1] + sh[2] + sh[3];
}

__global__ __launch_bounds__(256) void emd_finalize(const float* __restrict__ epart,
                                                    float* __restrict__ out) {
    __shared__ float sh[4];
    int b = blockIdx.x;
    int t = threadIdx.x;
    float s = epart[b * 512 + t] + epart[b * 512 + 256 + t];
    s = blockReduceSum256(s, sh);
    if (t == 0) out[b] = s;
}

extern "C" void kernel_launch(void* const* d_in, const int* in_sizes, int n_in,
                              void* d_out, int out_size, void* d_ws, size_t ws_size,
                              hipStream_t stream) {
    const float* a = (const float*)d_in[0];
    const float* b = (const float*)d_in[1];
    float* out = (float*)d_out;

    const size_t MBs = 1024ull * 1024ull;
    char* ws = (char*)d_ws;
    unsigned short* C16 = (unsigned short*)ws;              // 64 MB
    short* ahi   = (short*)(ws + 64 * MBs);                 // 2 MB each
    short* alo   = (short*)(ws + 66 * MBs);
    short* bhi   = (short*)(ws + 68 * MBs);
    short* blo   = (short*)(ws + 70 * MBs);
    unsigned* rminp = (unsigned*)(ws + 72 * MBs);           // 1 MB (16 jtiles)
    unsigned* cminp = (unsigned*)(ws + 74 * MBs);           // 1 MB (16 itiles)
    unsigned* rlist = (unsigned*)(ws + 64 * MBs);           // 32 MB, alias (after weights)
    unsigned* clist = (unsigned*)(ws + 96 * MBs);           // 32 MB
    char* tail = ws + 128 * MBs;
    size_t off = 0;
    const size_t szV = (size_t)NB * PP * 4;                 // 64 KB
    int*   scnt    = (int*)(tail + off); off += (size_t)NB * PP * 4 * 4;
    unsigned* rowminp = (unsigned*)(tail + off); off += szV;
    unsigned* colminp = (unsigned*)(tail + off); off += szV;
    float* rowminf = (float*)(tail + off); off += szV;
    float* colminf = (float*)(tail + off); off += szV;
    float* cthresh = (float*)(tail + off); off += szV;
    float* elm     = (float*)(tail + off); off += szV;
    float* eln     = (float*)(tail + off); off += szV;
    float* u       = (float*)(tail + off); off += szV;
    float* v       = (float*)(tail + off); off += szV;
    float* du      = (float*)(tail + off); off += szV;
    int*   rcnt    = (int*)(tail + off); off += szV;
    float* Sa      = (float*)(tail + off); off += (size_t)2 * NB * DD * 4; // Sa+Sb
    float* Sb      = Sa + NB * DD;
    float* epart   = (float*)(tail + off); off += (size_t)NB * PP / 4 * 4;
    int*   conv    = (int*)(tail + off); off += 64;
    if (ws_size < 128 * MBs + off) return;

    norm_kernel<<<(2 * NB * PP) / 4, 256, 0, stream>>>(a, b, ahi, alo, bhi, blo,
            u, v, conv, out, Sa);
    sumvec_kernel<<<64, 256, 0, stream>>>(ahi, alo, bhi, blo, Sa, Sb);
    cost_kernel<<<dim3(PP / 128, PP / 128, NB), 256, 0, stream>>>(
            ahi, alo, bhi, blo, C16, rminp, cminp);
    combine_kernel<<<64, 256, 0, stream>>>(rminp, cminp, rowminp, colminp);
    weights_kernel<<<16, 256, 0, stream>>>(Sa, Sb, ahi, alo, bhi, blo,
            rowminp, colminp, elm, eln, rowminf, colminf, cthresh);
    select_kernel<<<4096 + 1024, 256, 0, stream>>>(C16, colminf, rowminf,
            cthresh, rlist, rcnt, clist, scnt);
    for (int it = 0; it < TMAX; ++it) {
        u_kernel<<<NB * PP / 4, 256, 0, stream>>>(rlist, rcnt, v, elm, u, du, conv);
        v_kernel<<<NB * PP / 4, 256, 0, stream>>>(clist, scnt, u, eln, v, du, conv);
    }
    emd_kernel<<<NB * PP / 4, 256, 0, stream>>>(rlist, rcnt, u, v, epart);
    emd_finalize<<<NB, 256, 0, stream>>>(epart, out);
}

// Round 3
// 330.878 us; speedup vs baseline: 1.0958x; 1.0144x over previous
//
#include <hip/hip_runtime.h>
#include <math.h>

#define NB 8
#define PP 2048
#define DD 64
#define EPSF 1e-3f
#define RCPE 1000.0f
#define TMAX 10
#define THRESHF 0.1f
#define NEG_INF (-1e30f)
#define QSCALE 32767.5f                 // cost in [0,2] -> u16
#define S_DEQ  (1.0f / 32767.5f)
#define KR 512                          // row candidate cap
#define KC 512                          // col candidate cap (4 segs x 128)
#define TSEL 0.15f                      // selection margin (PROVEN: 0.12 fails, r6)
// NOTE (r8): cooperative grid.sync costs ~115 us/sync on gfx950. Do not retry.
// NOTE (r12): folding combine into 16-block weights => latency collapse.
// NOTE (r15): col select with 2B/lane strided loads => 2x regression.
// NOTE (r17): emd atomicAdd x4096 to ONE cacheline (out[0..7]) = 55us of
//             serialized RMW. Partials + 8-block finalize instead.
// NOTE (r18): cost_kernel occupancy 18->37% (VGPR 120->52) left dur FLAT at
//             56us. NOT occupancy-bound => was ILP/latency. r19 LDS-staged B
//             (XOR swizzle) + pknorm epilogue fixed it: cost now <46us.
// NOTE (r20): select was 46us, VALU 41%, all else idle: serialized 32-step
//             ballot chain (row) + 128 LDS atomics/thread (col). Replaced
//             with reg-cached diffs + single wave scan + count-then-append.

typedef __attribute__((ext_vector_type(8))) short bf16x8;
typedef __attribute__((ext_vector_type(4))) float f32x4;

__device__ __forceinline__ float waveAllMax(float v) {
#pragma unroll
    for (int m = 1; m < 64; m <<= 1) v = fmaxf(v, __shfl_xor(v, m, 64));
    return v;
}
__device__ __forceinline__ float waveAllMin(float v) {
#pragma unroll
    for (int m = 1; m < 64; m <<= 1) v = fminf(v, __shfl_xor(v, m, 64));
    return v;
}
__device__ __forceinline__ float waveAllSum(float v) {
#pragma unroll
    for (int m = 1; m < 64; m <<= 1) v += __shfl_xor(v, m, 64);
    return v;
}
__device__ __forceinline__ short f2bf(float x) {   // round-to-nearest-even bf16
    unsigned b = __float_as_uint(x);
    return (short)((b + 0x7FFFu + ((b >> 16) & 1u)) >> 16);
}
__device__ __forceinline__ float bf2f(short h) {
    return __uint_as_float(((unsigned)(unsigned short)h) << 16);
}
// fused: clamp(f,0,1)*65535, round, pack 2 -> u32  (== round(cost*32767.5))
__device__ __forceinline__ unsigned pknorm_u16(float a, float b) {
    unsigned r;
    asm("v_cvt_pknorm_u16_f32 %0, %1, %2" : "=v"(r) : "v"(a), "v"(b));
    return r;
}

// ---- L2 normalize + bf16 hi/lo split (+ init of u/v/conv/out/Sa/Sb) --------
__global__ void norm_kernel(const float* __restrict__ a, const float* __restrict__ b,
                            short* __restrict__ ahi, short* __restrict__ alo,
                            short* __restrict__ bhi, short* __restrict__ blo,
                            float* __restrict__ u, float* __restrict__ v,
                            int* __restrict__ conv, float* __restrict__ out,
                            float* __restrict__ Sa) {
    int gt = blockIdx.x * 256 + threadIdx.x;
    if (gt < NB * PP) { u[gt] = 0.0f; v[gt] = 0.0f; }
    if (gt == 0) *conv = 0;
    if (gt < NB) out[gt] = 0.0f;
    if (gt < 2 * NB * DD) Sa[gt] = 0.0f;       // Sa and Sb contiguous
    int wave = gt >> 6;
    int lane = threadIdx.x & 63;
    const float* src; short* dhi; short* dlo; int row;
    if (wave < NB * PP) { src = a; dhi = ahi; dlo = alo; row = wave; }
    else                { src = b; dhi = bhi; dlo = blo; row = wave - NB * PP; }
    float x = src[(size_t)row * DD + lane];
    float ss = waveAllSum(x * x);
    float r = 1.0f / fmaxf(sqrtf(ss), 1e-12f);
    float xn = x * r;
    short h = f2bf(xn);
    dhi[(size_t)row * DD + lane] = h;
    dlo[(size_t)row * DD + lane] = f2bf(xn - bf2f(h));
}

// ---- per-batch dim-wise sums: Sa[b][d] = sum_i a_n[i][d] (same for Sb) -----
__global__ void sumvec_kernel(const short* __restrict__ ahi, const short* __restrict__ alo,
                              const short* __restrict__ bhi, const short* __restrict__ blo,
                              float* __restrict__ Sa, float* __restrict__ Sb) {
    // 64 blocks: b (3b) | isB (1b) | quarter (2b)
    int b = blockIdx.x >> 3;
    bool isB = (blockIdx.x >> 2) & 1;
    int qtr = blockIdx.x & 3;
    const short* hi = (isB ? bhi : ahi) + ((size_t)b * PP + qtr * 512) * DD;
    const short* lo = (isB ? blo : alo) + ((size_t)b * PP + qtr * 512) * DD;
    float* dst = (isB ? Sb : Sa) + b * DD;
    int t = threadIdx.x;
    int w = t >> 6, lane = t & 63;
    int rl = lane >> 3, dq = lane & 7;       // row-in-group, dim-octet
    float s[8] = {};
#pragma unroll
    for (int it = 0; it < 16; ++it) {
        size_t o = (size_t)(w * 128 + it * 8 + rl) * DD + dq * 8;
        bf16x8 h = *(const bf16x8*)(hi + o);
        bf16x8 l = *(const bf16x8*)(lo + o);
#pragma unroll
        for (int e = 0; e < 8; ++e) s[e] += bf2f(h[e]) + bf2f(l[e]);
    }
#pragma unroll
    for (int e = 0; e < 8; ++e) {
#pragma unroll
        for (int m = 8; m < 64; m <<= 1) s[e] += __shfl_xor(s[e], m, 64);
    }
    __shared__ float sh[4][64];
    if (rl == 0) {
#pragma unroll
        for (int e = 0; e < 8; ++e) sh[w][dq * 8 + e] = s[e];
    }
    __syncthreads();
    if (t < 64) atomicAdd(&dst[t], sh[0][t] + sh[1][t] + sh[2][t] + sh[3][t]);
}

// ---- cost GEMM: 128x128 tile, LDS-staged B (XOR swizzle), pknorm epilogue --
// wave w owns rows [w*32, w*32+32); cols split nh*64 + li*4 + ntl.
__global__ __launch_bounds__(256, 4) void cost_kernel(const short* __restrict__ ahi,
        const short* __restrict__ alo, const short* __restrict__ bhi,
        const short* __restrict__ blo, unsigned short* __restrict__ C16,
        unsigned* __restrict__ rminp, unsigned* __restrict__ cminp) {
    __shared__ short Bs[2][128 * 64];        // [hi/lo][col][dim], LDS[x]=G[swz(x)]
    __shared__ unsigned cmin2[4][128];
    int b  = blockIdx.z;
    int i0 = blockIdx.y * 128;
    int j0 = blockIdx.x * 128;
    int t = threadIdx.x, w = t >> 6, lane = t & 63;
    int quad = lane >> 4, li = lane & 15;
    // ---- stage B panel (hi+lo, 32 KB) with write-side inverse swizzle ------
    const char* bh = (const char*)(bhi + ((size_t)b * PP + j0) * DD);
    const char* bl = (const char*)(blo + ((size_t)b * PP + j0) * DD);
    uint4 st[8];
#pragma unroll
    for (int i = 0; i < 4; ++i) {
        unsigned x = (unsigned)(t + i * 256) * 16;
        unsigned sx = x ^ (((x >> 7) & 7u) << 4);
        st[i]     = *(const uint4*)(bh + sx);
        st[4 + i] = *(const uint4*)(bl + sx);
    }
#pragma unroll
    for (int i = 0; i < 4; ++i) {
        unsigned x = (unsigned)(t + i * 256) * 16;
        *(uint4*)((char*)&Bs[0][0] + x) = st[i];
        *(uint4*)((char*)&Bs[1][0] + x) = st[4 + i];
    }
    __syncthreads();
    // ---- MFMA main: bf16 hi/lo split (hh + hl + lh) ------------------------
    size_t Aoff = ((size_t)b * PP + i0 + w * 32) * DD;
    f32x4 acc[2][2][4] = {};                 // [mt][nh][ntl]
#pragma unroll
    for (int kc = 0; kc < 2; ++kc) {
        int k0 = kc * 32 + quad * 8;
        bf16x8 fah[2], fal[2];
#pragma unroll
        for (int mt = 0; mt < 2; ++mt) {
            size_t o = Aoff + (size_t)(mt * 16 + li) * DD + k0;
            fah[mt] = *(const bf16x8*)(ahi + o);
            fal[mt] = *(const bf16x8*)(alo + o);
        }
#pragma unroll
        for (int nh = 0; nh < 2; ++nh) {
#pragma unroll
            for (int ntl = 0; ntl < 4; ++ntl) {
                int col = nh * 64 + li * 4 + ntl;
                unsigned xo = ((unsigned)col * 128 + (unsigned)(kc * 4 + quad) * 16)
                              ^ (((unsigned)col & 7u) << 4);
                bf16x8 fbh = *(const bf16x8*)((const char*)&Bs[0][0] + xo);
                bf16x8 fbl = *(const bf16x8*)((const char*)&Bs[1][0] + xo);
#pragma unroll
                for (int mt = 0; mt < 2; ++mt) {
                    acc[mt][nh][ntl] = __builtin_amdgcn_mfma_f32_16x16x32_bf16(
                            fah[mt], fbh, acc[mt][nh][ntl], 0, 0, 0);
                    acc[mt][nh][ntl] = __builtin_amdgcn_mfma_f32_16x16x32_bf16(
                            fah[mt], fbl, acc[mt][nh][ntl], 0, 0, 0);
                    acc[mt][nh][ntl] = __builtin_amdgcn_mfma_f32_16x16x32_bf16(
                            fal[mt], fbh, acc[mt][nh][ntl], 0, 0, 0);
                }
            }
        }
    }
    // ---- epilogue: pknorm quant+pack store + row/col min partials ----------
    unsigned cmin[2][4] = {{0xFFFFFFFFu, 0xFFFFFFFFu, 0xFFFFFFFFu, 0xFFFFFFFFu},
                           {0xFFFFFFFFu, 0xFFFFFFFFu, 0xFFFFFFFFu, 0xFFFFFFFFu}};
#pragma unroll
    for (int mt = 0; mt < 2; ++mt) {
#pragma unroll
        for (int r = 0; r < 4; ++r) {
            int irow = w * 32 + mt * 16 + quad * 4 + r;   // local row 0..127
            unsigned rm = 0xFFFFFFFFu;
            unsigned rowkey = (unsigned)(i0 + irow);
#pragma unroll
            for (int nh = 0; nh < 2; ++nh) {
                float f0 = fmaf(acc[mt][nh][0][r], -0.5f, 0.5f);
                float f1 = fmaf(acc[mt][nh][1][r], -0.5f, 0.5f);
                float f2 = fmaf(acc[mt][nh][2][r], -0.5f, 0.5f);
                float f3 = fmaf(acc[mt][nh][3][r], -0.5f, 0.5f);
                unsigned w0 = pknorm_u16(f0, f1);
                unsigned w1 = pknorm_u16(f2, f3);
                uint2 pv; pv.x = w0; pv.y = w1;
                *(uint2*)&C16[((size_t)b * PP + i0 + irow) * PP + j0 + nh * 64 + li * 4] = pv;
                unsigned colb = (unsigned)(j0 + nh * 64 + li * 4);
                unsigned lo0 = w0 << 16, hi0 = w0 & 0xFFFF0000u;
                unsigned lo1 = w1 << 16, hi1 = w1 & 0xFFFF0000u;
                rm = min(rm, min(min(lo0 | colb, hi0 | (colb + 1)),
                                 min(lo1 | (colb + 2), hi1 | (colb + 3))));
                cmin[nh][0] = min(cmin[nh][0], lo0 | rowkey);
                cmin[nh][1] = min(cmin[nh][1], hi0 | rowkey);
                cmin[nh][2] = min(cmin[nh][2], lo1 | rowkey);
                cmin[nh][3] = min(cmin[nh][3], hi1 | rowkey);
            }
#pragma unroll
            for (int m = 1; m < 16; m <<= 1)
                rm = min(rm, (unsigned)__shfl_xor((int)rm, m, 64));
            if (li == 0)        // wave owns its rows exclusively: direct store
                rminp[(size_t)blockIdx.x * (NB * PP) + b * PP + i0 + irow] = rm;
        }
    }
#pragma unroll
    for (int nh = 0; nh < 2; ++nh) {
#pragma unroll
        for (int ntl = 0; ntl < 4; ++ntl) {
            unsigned cmv = cmin[nh][ntl];
            cmv = min(cmv, (unsigned)__shfl_xor((int)cmv, 16, 64));
            cmv = min(cmv, (unsigned)__shfl_xor((int)cmv, 32, 64));
            if (quad == 0) cmin2[w][nh * 64 + li * 4 + ntl] = cmv;
        }
    }
    __syncthreads();
    if (t < 128)
        cminp[(size_t)blockIdx.y * (NB * PP) + b * PP + j0 + t] =
            min(min(cmin2[0][t], cmin2[1][t]), min(cmin2[2][t], cmin2[3][t]));
}

// ---- combine min partials (wide grid: 64 blocks) ---------------------------
__global__ void combine_kernel(const unsigned* __restrict__ rminp,
                               const unsigned* __restrict__ cminp,
                               unsigned* __restrict__ rowminp, unsigned* __restrict__ colminp) {
    int idx = blockIdx.x * 256 + threadIdx.x;
    unsigned rm = 0xFFFFFFFFu, cm = 0xFFFFFFFFu;
#pragma unroll
    for (int k = 0; k < 16; ++k)
        rm = min(rm, rminp[(size_t)k * (NB * PP) + idx]);
#pragma unroll
    for (int k = 0; k < 16; ++k)
        cm = min(cm, cminp[(size_t)k * (NB * PP) + idx]);
    rowminp[idx] = rm; colminp[idx] = cm;
}

// ---- weights + thresholds (rowS/colS computed algebraically: a_i . Sb) -----
__device__ __forceinline__ float blockReduceSum256(float v, float* sh) {
    v = waveAllSum(v);
    int lane = threadIdx.x & 63, w = threadIdx.x >> 6;
    if (lane == 0) sh[w] = v;
    __syncthreads();
    float r = sh[0] + sh[1] + sh[2] + sh[3];
    __syncthreads();
    return r;
}

__global__ void weights_kernel(const float* __restrict__ Sa, const float* __restrict__ Sb,
                               const short* __restrict__ ahi, const short* __restrict__ alo,
                               const short* __restrict__ bhi, const short* __restrict__ blo,
                               const unsigned* __restrict__ rowminp, const unsigned* __restrict__ colminp,
                               float* __restrict__ elm, float* __restrict__ eln,
                               float* __restrict__ rowminf, float* __restrict__ colminf,
                               float* __restrict__ cthresh) {
    __shared__ float sh[4];
    __shared__ float sv[64];
    int b = blockIdx.x & 7;
    bool isB = blockIdx.x >= 8;
    const short* hi = (isB ? bhi : ahi) + (size_t)b * PP * DD;
    const short* lo = (isB ? blo : alo) + (size_t)b * PP * DD;
    const float* svecg = (isB ? Sa : Sb) + b * DD;   // b_j . Sa  /  a_i . Sb
    float* dst = (isB ? eln : elm) + b * PP;
    int tid = threadIdx.x;
    if (tid < 64) sv[tid] = svecg[tid];
    __syncthreads();
    float x[8];
    float sabs = 0.0f;
#pragma unroll
    for (int q = 0; q < 8; ++q) {
        int row = tid + q * 256;
        float dot = 0.0f;
#pragma unroll
        for (int dq = 0; dq < 8; ++dq) {
            bf16x8 h = *(const bf16x8*)(hi + (size_t)row * DD + dq * 8);
            bf16x8 l = *(const bf16x8*)(lo + (size_t)row * DD + dq * 8);
#pragma unroll
            for (int e = 0; e < 8; ++e)
                dot += (bf2f(h[e]) + bf2f(l[e])) * sv[dq * 8 + e];
        }
        x[q] = dot * (1.0f / (float)PP);
        sabs += fabsf(x[q]);
    }
    sabs = blockReduceSum256(sabs, sh);
    float inv1 = 1.0f / fmaxf(sabs, 1e-12f);
    float spos = 0.0f;
#pragma unroll
    for (int q = 0; q < 8; ++q) {
        x[q] = fmaxf(x[q] * inv1, 0.0f);
        spos += x[q];
    }
    spos = blockReduceSum256(spos, sh);
    float inv2 = 1.0f / fmaxf(spos, 1e-12f);
#pragma unroll
    for (int q = 0; q < 8; ++q)
        dst[tid + q * 256] = EPSF * logf(x[q] * inv2 + 1e-8f);
    if (isB) {
#pragma unroll
        for (int q = 0; q < 8; ++q) {
            int idx = b * PP + tid + q * 256;
            unsigned pc = colminp[idx];
            unsigned arg = pc & 0xffffu;
            unsigned pr = rowminp[b * PP + arg];
            float cmf = (float)(pc >> 16) * S_DEQ;
            colminf[idx] = cmf;
            cthresh[idx] = cmf - (float)(pr >> 16) * S_DEQ + TSEL;
        }
    } else {
#pragma unroll
        for (int q = 0; q < 8; ++q) {
            int idx = b * PP + tid + q * 256;
            rowminf[idx] = (float)(rowminp[idx] >> 16) * S_DEQ;
        }
    }
}

// ---- fused candidate selection: blocks [0,4096) rows, [4096,5120) col qtrs -
__global__ __launch_bounds__(256) void select_kernel(const unsigned short* __restrict__ C16,
        const float* __restrict__ colminf, const float* __restrict__ rowminf,
        const float* __restrict__ cthresh,
        unsigned* __restrict__ rlist, int* __restrict__ rcnt,
        unsigned* __restrict__ clist, int* __restrict__ scnt) {
    __shared__ unsigned tile32[64][36];
    __shared__ float rm_s[64];
    __shared__ unsigned lcnt[64];
    if (blockIdx.x < 4096) {
        // ---- row path: wave per row; diffs in regs, scan-based compaction --
        int w = threadIdx.x >> 6, lane = threadIdx.x & 63;
        int row = blockIdx.x * 4 + w;
        int b = row >> 11;
        const uint4* cp = (const uint4*)(C16 + (size_t)row * PP);
        uint4 q4[4];
#pragma unroll
        for (int g = 0; g < 4; ++g) q4[g] = cp[g * 64 + lane];
        const float* cmb = colminf + b * PP;
        float d[32];                         // cf - colminf, kept in regs
        float rpmin = 1e30f;
#pragma unroll
        for (int g = 0; g < 4; ++g) {
            int jb = g * 512 + lane * 8;
            float4 cm0 = *(const float4*)(cmb + jb);
            float4 cm1 = *(const float4*)(cmb + jb + 4);
            float cm[8] = {cm0.x, cm0.y, cm0.z, cm0.w, cm1.x, cm1.y, cm1.z, cm1.w};
            unsigned qq[4] = {q4[g].x, q4[g].y, q4[g].z, q4[g].w};
#pragma unroll
            for (int h = 0; h < 4; ++h) {
                float c0 = (float)(qq[h] & 0xffffu) * S_DEQ;
                float c1 = (float)(qq[h] >> 16) * S_DEQ;
                d[g * 8 + h * 2]     = c0 - cm[h * 2];
                d[g * 8 + h * 2 + 1] = c1 - cm[h * 2 + 1];
                rpmin = fminf(rpmin, fminf(d[g * 8 + h * 2], d[g * 8 + h * 2 + 1]));
            }
        }
        float rth = waveAllMin(rpmin) + TSEL;
        // per-lane count -> wave exclusive scan -> exclusive-range writes
        int cnt = 0;
#pragma unroll
        for (int e = 0; e < 32; ++e) cnt += (d[e] <= rth) ? 1 : 0;
        int inc = cnt;
#pragma unroll
        for (int m = 1; m < 64; m <<= 1) {
            int t2 = __shfl_up(inc, m, 64);
            if (lane >= m) inc += t2;
        }
        int p = inc - cnt;                   // exclusive prefix
        unsigned* rl = rlist + (size_t)row * KR;
#pragma unroll
        for (int g = 0; g < 4; ++g) {
            int jb = g * 512 + lane * 8;
            unsigned qq[4] = {q4[g].x, q4[g].y, q4[g].z, q4[g].w};
#pragma unroll
            for (int e = 0; e < 8; ++e) {
                if (d[g * 8 + e] <= rth) {
                    unsigned q = (qq[e >> 1] >> ((e & 1) * 16)) & 0xffffu;
                    if (p < KR) rl[p] = ((unsigned)(jb + e) << 16) | q;
                    ++p;
                }
            }
        }
        if (lane == 63) rcnt[row] = inc;     // inclusive total at last lane
    } else {
        // ---- col path: (b, slab, quarter); mask+count, 1 atomic per chunk --
        int bid = blockIdx.x - 4096;         // 0..1023
        int b = bid >> 7;
        int rem = bid & 127;
        int j0 = (rem >> 2) * 64;
        int r0 = (rem & 3) * 512;
        int qq = rem & 3;
        int t = threadIdx.x;
        int col = t & 63, seg = t >> 6;
        float ctj = cthresh[b * PP + j0 + col];
        unsigned* mylist = clist + ((size_t)(b * PP + j0 + col)) * KC + qq * 128;
        if (t < 64) lcnt[t] = 0;
        int lrow = t >> 3, lcc = t & 7;
        uint4 pf0, pf1; float pfr = 0.0f;
        {
            const unsigned short* base0 = C16 + ((size_t)b * PP + r0 + lrow) * PP + j0;
            pf0 = ((const uint4*)base0)[lcc];
            pf1 = ((const uint4*)(base0 + (size_t)32 * PP))[lcc];
            if (t < 64) pfr = rowminf[b * PP + r0 + t];
        }
        for (int chunk = 0; chunk < 8; ++chunk) {
            *(uint4*)&tile32[lrow][lcc * 4]      = pf0;
            *(uint4*)&tile32[32 + lrow][lcc * 4] = pf1;
            if (t < 64) rm_s[t] = pfr;
            __syncthreads();
            if (chunk < 7) {
                int rn = r0 + (chunk + 1) * 64;
                const unsigned short* base0 = C16 + ((size_t)b * PP + rn + lrow) * PP + j0;
                pf0 = ((const uint4*)base0)[lcc];
                pf1 = ((const uint4*)(base0 + (size_t)32 * PP))[lcc];
                if (t < 64) pfr = rowminf[b * PP + rn + t];
            }
            int rbase = r0 + chunk * 64;
            unsigned qv[16];
            unsigned mask16 = 0;
            int sel = 0;
#pragma unroll
            for (int rr = 0; rr < 16; ++rr) {
                int rowl = seg * 16 + rr;
                unsigned w32 = tile32[rowl][col >> 1];
                unsigned q = (col & 1) ? (w32 >> 16) : (w32 & 0xffffu);
                qv[rr] = q;
                if ((float)q * S_DEQ - rm_s[rowl] <= ctj) { mask16 |= 1u << rr; ++sel; }
            }
            unsigned basep = sel ? atomicAdd(&lcnt[col], (unsigned)sel) : 0u;
#pragma unroll
            for (int rr = 0; rr < 16; ++rr) {
                if (mask16 & (1u << rr)) {
                    if (basep < 128)
                        mylist[basep] = ((unsigned)(rbase + seg * 16 + rr) << 16) | qv[rr];
                    ++basep;
                }
            }
            __syncthreads();
        }
        if (t < 64)
            scnt[(b * PP + j0 + t) * 4 + qq] = min((int)lcnt[t], 128);
    }
}

// ---- Sinkhorn u-update over row candidates (wave per row) ------------------
__global__ __launch_bounds__(256) void u_kernel(const unsigned* __restrict__ rlist,
        const int* __restrict__ rcnt, const float* __restrict__ v,
        const float* __restrict__ elm, float* __restrict__ u, float* __restrict__ du,
        const int* __restrict__ conv) {
    if (*conv) return;
    int w = threadIdx.x >> 6, lane = threadIdx.x & 63;
    int row = blockIdx.x * 4 + w;
    int b = row >> 11;
    int cnt = min(rcnt[row], KR);
    const unsigned* lst = rlist + (size_t)row * KR;
    const float* vb = v + (b << 11);
    float x[8];
    float m = NEG_INF;
#pragma unroll
    for (int s = 0; s < 8; ++s) {
        int e = lane + s * 64;
        x[s] = NEG_INF;
        if (e < cnt) {
            unsigned wd = lst[e];
            x[s] = vb[wd >> 16] - (float)(wd & 0xffffu) * S_DEQ;
        }
        m = fmaxf(m, x[s]);
    }
    m = waveAllMax(m);
    float s = 0.0f;
#pragma unroll
    for (int k = 0; k < 8; ++k) s += __expf((x[k] - m) * RCPE);
    s = waveAllSum(s);
    if (lane == 0) {
        float un = elm[row] - m - EPSF * logf(s);
        du[row] = fabsf(un - u[row]);
        u[row] = un;
    }
}

// ---- Sinkhorn v-update over col candidates (+ err/conv in block 0) ---------
__global__ __launch_bounds__(256) void v_kernel(const unsigned* __restrict__ clist,
        const int* __restrict__ scnt, const float* __restrict__ u,
        const float* __restrict__ eln, float* __restrict__ v,
        const float* __restrict__ du, int* __restrict__ conv) {
    if (*conv) return;
    int w = threadIdx.x >> 6, lane = threadIdx.x & 63;
    int jg = blockIdx.x * 4 + w;
    int b = jg >> 11;
    int4 sc = *(const int4*)&scnt[jg * 4];
    int cn[4] = {sc.x, sc.y, sc.z, sc.w};
    const unsigned* lst = clist + (size_t)jg * KC;
    const float* ub = u + (b << 11);
    float x[8];
    float m = NEG_INF;
#pragma unroll
    for (int s = 0; s < 8; ++s) {
        int e = lane + s * 64;
        int sg = e >> 7, k = e & 127;
        x[s] = NEG_INF;
        if (k < cn[sg]) {
            unsigned wd = lst[sg * 128 + k];
            x[s] = ub[wd >> 16] - (float)(wd & 0xffffu) * S_DEQ;
        }
        m = fmaxf(m, x[s]);
    }
    m = waveAllMax(m);
    float s = 0.0f;
#pragma unroll
    for (int k = 0; k < 8; ++k) s += __expf((x[k] - m) * RCPE);
    s = waveAllSum(s);
    if (lane == 0)
        v[jg] = eln[jg] - m - EPSF * logf(s);
    if (blockIdx.x == 0) {
        __shared__ float sh[4];
        int t = threadIdx.x;
        float sacc = 0.0f;
#pragma unroll
        for (int q = 0; q < 64; ++q) sacc += du[t + q * 256];
        sacc = waveAllSum(sacc);
        if (lane == 0) sh[w] = sacc;
        __syncthreads();
        if (t == 0) {
            float tot = sh[0] + sh[1] + sh[2] + sh[3];
            if (tot * (1.0f / (float)NB) < THRESHF) *conv = 1;
        }
    }
}

// ---- final: block partials (no atomics) + 8-block finalize -----------------
__global__ __launch_bounds__(256) void emd_kernel(const unsigned* __restrict__ rlist,
        const int* __restrict__ rcnt, const float* __restrict__ u,
        const float* __restrict__ v, float* __restrict__ epart) {
    __shared__ float sh[4];
    int w = threadIdx.x >> 6, lane = threadIdx.x & 63;
    int row = blockIdx.x * 4 + w;
    int b = row >> 11;
    int cnt = min(rcnt[row], KR);
    const unsigned* lst = rlist + (size_t)row * KR;
    const float* vb = v + (b << 11);
    float ui = u[row];
    float s = 0.0f;
#pragma unroll
    for (int k = 0; k < 8; ++k) {
        int e = lane + k * 64;
        if (e < cnt) {
            unsigned wd = lst[e];
            float cf = (float)(wd & 0xffffu) * S_DEQ;
            s += __expf((ui + vb[wd >> 16] - cf) * RCPE) * cf;
        }
    }
    s = waveAllSum(s);
    if (lane == 0) sh[w] = s;
    __syncthreads();
    if (threadIdx.x == 0) epart[blockIdx.x] = sh[0] + sh[1] + sh[2] + sh[3];
}

__global__ __launch_bounds__(256) void emd_finalize(const float* __restrict__ epart,
                                                    float* __restrict__ out) {
    __shared__ float sh[4];
    int b = blockIdx.x;
    int t = threadIdx.x;
    float s = epart[b * 512 + t] + epart[b * 512 + 256 + t];
    s = blockReduceSum256(s, sh);
    if (t == 0) out[b] = s;
}

extern "C" void kernel_launch(void* const* d_in, const int* in_sizes, int n_in,
                              void* d_out, int out_size, void* d_ws, size_t ws_size,
                              hipStream_t stream) {
    const float* a = (const float*)d_in[0];
    const float* b = (const float*)d_in[1];
    float* out = (float*)d_out;

    const size_t MBs = 1024ull * 1024ull;
    char* ws = (char*)d_ws;
    unsigned short* C16 = (unsigned short*)ws;              // 64 MB
    short* ahi   = (short*)(ws + 64 * MBs);                 // 2 MB each
    short* alo   = (short*)(ws + 66 * MBs);
    short* bhi   = (short*)(ws + 68 * MBs);
    short* blo   = (short*)(ws + 70 * MBs);
    unsigned* rminp = (unsigned*)(ws + 72 * MBs);           // 1 MB (16 jtiles)
    unsigned* cminp = (unsigned*)(ws + 74 * MBs);           // 1 MB (16 itiles)
    unsigned* rlist = (unsigned*)(ws + 64 * MBs);           // 32 MB, alias (after weights)
    unsigned* clist = (unsigned*)(ws + 96 * MBs);           // 32 MB
    char* tail = ws + 128 * MBs;
    size_t off = 0;
    const size_t szV = (size_t)NB * PP * 4;                 // 64 KB
    int*   scnt    = (int*)(tail + off); off += (size_t)NB * PP * 4 * 4;
    unsigned* rowminp = (unsigned*)(tail + off); off += szV;
    unsigned* colminp = (unsigned*)(tail + off); off += szV;
    float* rowminf = (float*)(tail + off); off += szV;
    float* colminf = (float*)(tail + off); off += szV;
    float* cthresh = (float*)(tail + off); off += szV;
    float* elm     = (float*)(tail + off); off += szV;
    float* eln     = (float*)(tail + off); off += szV;
    float* u       = (float*)(tail + off); off += szV;
    float* v       = (float*)(tail + off); off += szV;
    float* du      = (float*)(tail + off); off += szV;
    int*   rcnt    = (int*)(tail + off); off += szV;
    float* Sa      = (float*)(tail + off); off += (size_t)2 * NB * DD * 4; // Sa+Sb
    float* Sb      = Sa + NB * DD;
    float* epart   = (float*)(tail + off); off += (size_t)NB * PP / 4 * 4;
    int*   conv    = (int*)(tail + off); off += 64;
    if (ws_size < 128 * MBs + off) return;

    norm_kernel<<<(2 * NB * PP) / 4, 256, 0, stream>>>(a, b, ahi, alo, bhi, blo,
            u, v, conv, out, Sa);
    sumvec_kernel<<<64, 256, 0, stream>>>(ahi, alo, bhi, blo, Sa, Sb);
    cost_kernel<<<dim3(PP / 128, PP / 128, NB), 256, 0, stream>>>(
            ahi, alo, bhi, blo, C16, rminp, cminp);
    combine_kernel<<<64, 256, 0, stream>>>(rminp, cminp, rowminp, colminp);
    weights_kernel<<<16, 256, 0, stream>>>(Sa, Sb, ahi, alo, bhi, blo,
            rowminp, colminp, elm, eln, rowminf, colminf, cthresh);
    select_kernel<<<4096 + 1024, 256, 0, stream>>>(C16, colminf, rowminf,
            cthresh, rlist, rcnt, clist, scnt);
    for (int it = 0; it < TMAX; ++it) {
        u_kernel<<<NB * PP / 4, 256, 0, stream>>>(rlist, rcnt, v, elm, u, du, conv);
        v_kernel<<<NB * PP / 4, 256, 0, stream>>>(clist, scnt, u, eln, v, du, conv);
    }
    emd_kernel<<<NB * PP / 4, 256, 0, stream>>>(rlist, rcnt, u, v, epart);
    emd_finalize<<<NB, 256, 0, stream>>>(epart, out);
}